// Round 9
// baseline (23.890 us; speedup 1.0000x reference)
//
#include <hip/hip_runtime.h>

// VocabParallelEmbeddingWithLoRA — single kernel, no inter-block deps, no
// lora_b LDS staging (direct global->register: each d-row = 16 floats = one
// 64 B line, so per-thread row loads have zero line waste).
// out[t, d] = base_weight[base_idx(t), d] + sum_r a[t,r] * lora_b[li[t], d, r]
//   a[t,:]      = lora_a[li[t], x[t], :]
//   base_idx(t) = x[t] + (x[t] >= ORG_VOCAB ? li[t]*EXTRA : 0)
//
// Block = (lora l, stripe of 64 tokens, d-chunk of 512): 8*64*4 = 2048 blocks.
// Per block: ballot match-list, gather a-vectors to LDS, bt rows in registers,
// then barrier-free double-buffered base-row prefetch + rank-16 FMA + store.

constexpr int ORG_VOCAB = 32000;
constexpr int EXTRA     = 256;
constexpr int RANK      = 16;
constexpr int D         = 2048;
constexpr int NLORA     = 8;
constexpr int SPLIT     = 64;              // token stripes
constexpr int SLEN      = 64;              // tokens per stripe (T=4096)
constexpr int DCHUNK    = 512;             // d-columns per block
constexpr int NY        = D / DCHUNK;      // 4
constexpr int BLK       = 256;

__device__ __forceinline__ void load_batch(
    float2* buf, int mb, int nm,
    const int* s_mt, const int* s_bidx,
    const float* __restrict__ base_w, int d0)
{
    #pragma unroll
    for (int i = 0; i < 8; ++i) {
        const int ii = (mb + i < nm) ? (mb + i) : (nm - 1);
        const int k  = s_mt[ii];
        buf[i] = *(const float2*)(base_w + (size_t)s_bidx[k] * D + d0);
    }
}

__device__ __forceinline__ void proc_batch(
    const float2* buf, int mb, int nm, int t0,
    const int* s_mt, const float (*s_a)[RANK],
    const float* bt0, const float* bt1,
    float* __restrict__ out, int d0)
{
    #pragma unroll
    for (int i = 0; i < 8; ++i) {
        if (mb + i >= nm) break;
        const int k  = s_mt[mb + i];
        const float4 a0 = *(const float4*)&s_a[mb + i][0];
        const float4 a1 = *(const float4*)&s_a[mb + i][4];
        const float4 a2 = *(const float4*)&s_a[mb + i][8];
        const float4 a3 = *(const float4*)&s_a[mb + i][12];
        float2 acc = buf[i];
        acc.x += a0.x*bt0[0]  + a0.y*bt0[1]  + a0.z*bt0[2]  + a0.w*bt0[3]
               + a1.x*bt0[4]  + a1.y*bt0[5]  + a1.z*bt0[6]  + a1.w*bt0[7]
               + a2.x*bt0[8]  + a2.y*bt0[9]  + a2.z*bt0[10] + a2.w*bt0[11]
               + a3.x*bt0[12] + a3.y*bt0[13] + a3.z*bt0[14] + a3.w*bt0[15];
        acc.y += a0.x*bt1[0]  + a0.y*bt1[1]  + a0.z*bt1[2]  + a0.w*bt1[3]
               + a1.x*bt1[4]  + a1.y*bt1[5]  + a1.z*bt1[6]  + a1.w*bt1[7]
               + a2.x*bt1[8]  + a2.y*bt1[9]  + a2.z*bt1[10] + a2.w*bt1[11]
               + a3.x*bt1[12] + a3.y*bt1[13] + a3.z*bt1[14] + a3.w*bt1[15];
        *(float2*)(out + (size_t)(t0 + k) * D + d0) = acc;
    }
}

__global__ __launch_bounds__(BLK, 4) void lora_fused_k(
    const int*   __restrict__ x,        // [T] token ids
    const int*   __restrict__ li,       // [T] lora indices
    const float* __restrict__ base_w,   // [ORG_VOCAB + NLORA*EXTRA, D]
    const float* __restrict__ lora_a,   // [NLORA, ORG_VOCAB+EXTRA, RANK]
    const float* __restrict__ lora_b,   // [NLORA, D, RANK]
    float*       __restrict__ out,      // [T, D]
    int T)
{
    const int l      = blockIdx.x >> 6;            // / SPLIT
    const int stripe = blockIdx.x & (SPLIT - 1);
    const int y      = blockIdx.y;
    const int tid    = threadIdx.x;
    const int t0     = stripe * SLEN;

    __shared__ int   s_tok[SLEN], s_bidx[SLEN], s_mt[SLEN];
    __shared__ int   s_nm;
    __shared__ float s_a[SLEN][RANK];              // 4 KB

    // ---- bt rows direct from global: rows 2*tid, 2*tid+1 of this d-chunk.
    // Each row = 16 floats = one 64 B line; 8 float4 loads, no line waste.
    // Issued first so their latency hides under the metadata phase.
    const float* __restrict__ brow =
        lora_b + ((size_t)l * D + (size_t)y * DCHUNK + 2 * tid) * RANK;
    float bt0[RANK], bt1[RANK];
    #pragma unroll
    for (int q = 0; q < 4; ++q) {
        *(float4*)&bt0[q * 4] = *(const float4*)(brow + q * 4);
        *(float4*)&bt1[q * 4] = *(const float4*)(brow + RANK + q * 4);
    }

    // ---- stripe metadata + match list (wave 0 covers the 64-token stripe) ----
    if (tid < SLEN) {
        const int t   = t0 + tid;
        const int lt  = (t < T) ? li[t] : -1;
        const int tok = (t < T) ? x[t] : 0;
        s_tok[tid]  = tok;
        s_bidx[tid] = tok + (tok >= ORG_VOCAB ? lt * EXTRA : 0);
        const bool f = (lt == l);
        const unsigned long long m = __ballot(f);
        const unsigned long long below = (1ull << tid) - 1ull;
        if (f) s_mt[__popcll(m & below)] = tid;
        if (tid == 0) s_nm = __popcll(m);
    }
    __syncthreads();

    const int nm = s_nm;
    if (nm == 0) return;

    // ---- gather ALL a-vectors up-front ----
    for (int j = tid; j < nm * RANK; j += BLK) {
        const int i = j >> 4, r = j & 15;
        s_a[i][r] = lora_a[((size_t)l * (ORG_VOCAB + EXTRA)
                            + (size_t)s_tok[s_mt[i]]) * RANK + r];
    }
    __syncthreads();

    // ---- barrier-free main loop, double-buffered prefetch ----
    const int d0 = y * DCHUNK + tid * 2;
    float2 bufA[8], bufB[8];

    load_batch(bufA, 0, nm, s_mt, s_bidx, base_w, d0);
    int mb = 0;
    while (true) {
        if (mb + 8 < nm) load_batch(bufB, mb + 8, nm, s_mt, s_bidx, base_w, d0);
        proc_batch(bufA, mb, nm, t0, s_mt, s_a, bt0, bt1, out, d0);
        mb += 8;
        if (mb >= nm) break;
        if (mb + 8 < nm) load_batch(bufA, mb + 8, nm, s_mt, s_bidx, base_w, d0);
        proc_batch(bufB, mb, nm, t0, s_mt, s_a, bt0, bt1, out, d0);
        mb += 8;
        if (mb >= nm) break;
    }
}

extern "C" void kernel_launch(void* const* d_in, const int* in_sizes, int n_in,
                              void* d_out, int out_size, void* d_ws, size_t ws_size,
                              hipStream_t stream) {
    const int*   x      = (const int*)d_in[0];
    const int*   li     = (const int*)d_in[1];
    const float* base_w = (const float*)d_in[2];
    const float* lora_a = (const float*)d_in[3];
    const float* lora_b = (const float*)d_in[4];
    float*       out    = (float*)d_out;

    int T = in_sizes[0];  // B*S = 4096

    dim3 grid(NLORA * SPLIT, NY);     // 512 x 4 = 2048 blocks
    lora_fused_k<<<grid, BLK, 0, stream>>>(x, li, base_w, lora_a, lora_b, out, T);
}

// Round 10
// 21.104 us; speedup vs baseline: 1.1320x; 1.1320x over previous
//
#include <hip/hip_runtime.h>

// VocabParallelEmbeddingWithLoRA — single kernel (R8 structure, best: 21.0 µs)
// + non-temporal output stores.
// out[t, d] = base_weight[base_idx(t), d] + sum_r a[t,r] * lora_b[li[t], d, r]
//   a[t,:]      = lora_a[li[t], x[t], :]
//   base_idx(t) = x[t] + (x[t] >= ORG_VOCAB ? li[t]*EXTRA : 0)
//
// Block = (lora l, stripe of 64 tokens, d-chunk of 512). 8*64*4 = 2048 blocks.
// Per block: stage 32 KB lora_b slice into LDS ([512][17] pad, contiguous
// float4 staging -> full-line reads), ballot match-list, gather a-vectors,
// then barrier-free double-buffered base-row prefetch + rank-16 FMA + store.

constexpr int ORG_VOCAB = 32000;
constexpr int EXTRA     = 256;
constexpr int RANK      = 16;
constexpr int D         = 2048;
constexpr int NLORA     = 8;
constexpr int SPLIT     = 64;              // token stripes
constexpr int SLEN      = 64;              // tokens per stripe (T=4096)
constexpr int DCHUNK    = 512;             // d-columns per block
constexpr int NY        = D / DCHUNK;      // 4
constexpr int BLK       = 256;

__device__ __forceinline__ void load_batch(
    float2* buf, int mb, int nm,
    const int* s_mt, const int* s_bidx,
    const float* __restrict__ base_w, int d0)
{
    #pragma unroll
    for (int i = 0; i < 8; ++i) {
        const int ii = (mb + i < nm) ? (mb + i) : (nm - 1);
        const int k  = s_mt[ii];
        buf[i] = *(const float2*)(base_w + (size_t)s_bidx[k] * D + d0);
    }
}

__device__ __forceinline__ void proc_batch(
    const float2* buf, int mb, int nm, int t0,
    const int* s_mt, const float (*s_a)[RANK],
    const float* bt0, const float* bt1,
    float* __restrict__ out, int d0)
{
    #pragma unroll
    for (int i = 0; i < 8; ++i) {
        if (mb + i >= nm) break;
        const int k  = s_mt[mb + i];
        const float4 a0 = *(const float4*)&s_a[mb + i][0];
        const float4 a1 = *(const float4*)&s_a[mb + i][4];
        const float4 a2 = *(const float4*)&s_a[mb + i][8];
        const float4 a3 = *(const float4*)&s_a[mb + i][12];
        float2 acc = buf[i];
        acc.x += a0.x*bt0[0]  + a0.y*bt0[1]  + a0.z*bt0[2]  + a0.w*bt0[3]
               + a1.x*bt0[4]  + a1.y*bt0[5]  + a1.z*bt0[6]  + a1.w*bt0[7]
               + a2.x*bt0[8]  + a2.y*bt0[9]  + a2.z*bt0[10] + a2.w*bt0[11]
               + a3.x*bt0[12] + a3.y*bt0[13] + a3.z*bt0[14] + a3.w*bt0[15];
        acc.y += a0.x*bt1[0]  + a0.y*bt1[1]  + a0.z*bt1[2]  + a0.w*bt1[3]
               + a1.x*bt1[4]  + a1.y*bt1[5]  + a1.z*bt1[6]  + a1.w*bt1[7]
               + a2.x*bt1[8]  + a2.y*bt1[9]  + a2.z*bt1[10] + a2.w*bt1[11]
               + a3.x*bt1[12] + a3.y*bt1[13] + a3.z*bt1[14] + a3.w*bt1[15];
        // Non-temporal: out is never re-read by the kernel; keep it from
        // polluting L2/L3 lines useful to the base-row gather.
        long long v;
        __builtin_memcpy(&v, &acc, 8);
        __builtin_nontemporal_store(v, (long long*)(out + (size_t)(t0 + k) * D + d0));
    }
}

__global__ __launch_bounds__(BLK, 4) void lora_fused_k(
    const int*   __restrict__ x,        // [T] token ids
    const int*   __restrict__ li,       // [T] lora indices
    const float* __restrict__ base_w,   // [ORG_VOCAB + NLORA*EXTRA, D]
    const float* __restrict__ lora_a,   // [NLORA, ORG_VOCAB+EXTRA, RANK]
    const float* __restrict__ lora_b,   // [NLORA, D, RANK]
    float*       __restrict__ out,      // [T, D]
    int T)
{
    const int l      = blockIdx.x >> 6;            // / SPLIT
    const int stripe = blockIdx.x & (SPLIT - 1);
    const int y      = blockIdx.y;
    const int tid    = threadIdx.x;
    const int t0     = stripe * SLEN;

    __shared__ float sb[DCHUNK][RANK + 1];         // 34.8 KB, 2-way-free reads
    __shared__ int   s_tok[SLEN], s_bidx[SLEN], s_mt[SLEN];
    __shared__ int   s_nm;
    __shared__ float s_a[SLEN][RANK];              // 4 KB

    // ---- stage lora_b slice: 32 KB contiguous, fully coalesced ----
    const float* __restrict__ bsrc =
        lora_b + ((size_t)l * D + (size_t)y * DCHUNK) * RANK;
    #pragma unroll
    for (int k = 0; k < (DCHUNK * RANK) / (BLK * 4); ++k) {   // 8 iters
        const int g4 = k * BLK + tid;              // float4 index in slice
        const float4 v = ((const float4*)bsrc)[g4];
        const int d  = g4 >> 2;
        const int r4 = (g4 & 3) * 4;
        sb[d][r4 + 0] = v.x; sb[d][r4 + 1] = v.y;
        sb[d][r4 + 2] = v.z; sb[d][r4 + 3] = v.w;
    }

    // ---- stripe metadata + match list (wave 0 covers the 64-token stripe) ----
    if (tid < SLEN) {
        const int t   = t0 + tid;
        const int lt  = (t < T) ? li[t] : -1;
        const int tok = (t < T) ? x[t] : 0;
        s_tok[tid]  = tok;
        s_bidx[tid] = tok + (tok >= ORG_VOCAB ? lt * EXTRA : 0);
        const bool f = (lt == l);
        const unsigned long long m = __ballot(f);
        const unsigned long long below = (1ull << tid) - 1ull;
        if (f) s_mt[__popcll(m & below)] = tid;
        if (tid == 0) s_nm = __popcll(m);
    }
    __syncthreads();

    const int nm = s_nm;
    if (nm == 0) return;

    // bt registers from LDS (rows 2*tid, 2*tid+1; pad-17 -> 2-way free)
    float bt0[RANK], bt1[RANK];
    #pragma unroll
    for (int r = 0; r < RANK; ++r) {
        bt0[r] = sb[2 * tid][r];
        bt1[r] = sb[2 * tid + 1][r];
    }

    // ---- gather ALL a-vectors up-front ----
    for (int j = tid; j < nm * RANK; j += BLK) {
        const int i = j >> 4, r = j & 15;
        s_a[i][r] = lora_a[((size_t)l * (ORG_VOCAB + EXTRA)
                            + (size_t)s_tok[s_mt[i]]) * RANK + r];
    }
    __syncthreads();

    // ---- barrier-free main loop, double-buffered prefetch ----
    const int d0 = y * DCHUNK + tid * 2;
    float2 bufA[8], bufB[8];

    load_batch(bufA, 0, nm, s_mt, s_bidx, base_w, d0);
    int mb = 0;
    while (true) {
        if (mb + 8 < nm) load_batch(bufB, mb + 8, nm, s_mt, s_bidx, base_w, d0);
        proc_batch(bufA, mb, nm, t0, s_mt, s_a, bt0, bt1, out, d0);
        mb += 8;
        if (mb >= nm) break;
        if (mb + 8 < nm) load_batch(bufA, mb + 8, nm, s_mt, s_bidx, base_w, d0);
        proc_batch(bufB, mb, nm, t0, s_mt, s_a, bt0, bt1, out, d0);
        mb += 8;
        if (mb >= nm) break;
    }
}

extern "C" void kernel_launch(void* const* d_in, const int* in_sizes, int n_in,
                              void* d_out, int out_size, void* d_ws, size_t ws_size,
                              hipStream_t stream) {
    const int*   x      = (const int*)d_in[0];
    const int*   li     = (const int*)d_in[1];
    const float* base_w = (const float*)d_in[2];
    const float* lora_a = (const float*)d_in[3];
    const float* lora_b = (const float*)d_in[4];
    float*       out    = (float*)d_out;

    int T = in_sizes[0];  // B*S = 4096

    dim3 grid(NLORA * SPLIT, NY);     // 512 x 4 = 2048 blocks
    lora_fused_k<<<grid, BLK, 0, stream>>>(x, li, base_w, lora_a, lora_b, out, T);
}